// Round 8
// baseline (52.953 us; speedup 1.0000x reference)
//
#include <hip/hip_runtime.h>

typedef float  v4f    __attribute__((ext_vector_type(4)));
typedef float  f32x4  __attribute__((ext_vector_type(4)));
typedef short  bf16x8 __attribute__((ext_vector_type(8)));
typedef short  bf16x4 __attribute__((ext_vector_type(4)));

namespace {
constexpr int XBSTR = 264;   // xbf row stride (bf16)
constexpr int XDSTR = 68;    // xd row stride (bf16)
constexpr int MWSTR = 132;   // mw row stride (f32)
constexpr int ASTR  = 264;   // att row stride (bf16)
constexpr int MSTR  = 72;    // mbf/abf row stride (bf16)
constexpr int NB    = 8;     // batches per block
constexpr int NIT   = 2;     // iterations of 4 batches
constexpr int FRAG_SLOTS = 5120;

__device__ __forceinline__ float fsilu(float v){ return v/(1.f+__expf(-v)); }
__device__ __forceinline__ float fsigm(float v){ return 1.f/(1.f+__expf(-v)); }
__device__ __forceinline__ short f2bf(float f){          // fp32 -> bf16 RNE
  unsigned u = __builtin_bit_cast(unsigned, f);
  return (short)((u + 0x7FFFu + ((u>>16)&1u)) >> 16);
}
__device__ __forceinline__ float bf2f(short s){
  unsigned u = ((unsigned)(unsigned short)s) << 16;
  return __builtin_bit_cast(float, u);
}

// ---- B-fragment getters: frag table in ws (fast) or on-the-fly (fallback) ----
template<bool USE_WS>
__device__ __forceinline__ bf16x8 get_bd(const bf16x8* wsf, const float* Wd,
                                         int nt, int ks, int l){
  if constexpr (USE_WS) return wsf[(nt*8 + ks)*64 + l];
  bf16x8 f;
  #pragma unroll
  for (int j = 0; j < 8; ++j) f[j] = f2bf(Wd[(ks*32 + (l>>4)*8 + j)*64 + nt*16 + (l&15)]);
  return f;
}
template<bool USE_WS>
__device__ __forceinline__ bf16x8 get_bc(const bf16x8* wsf, const float* Wc,
                                         int nt, int ks, int l){
  if constexpr (USE_WS) return wsf[2048 + (nt*2 + ks)*64 + l];
  const int col = nt*16 + (l&15), cw = col>>6, co = col&63;
  bf16x8 f;
  #pragma unroll
  for (int j = 0; j < 8; ++j) f[j] = f2bf(Wc[co*128 + cw*64 + ks*32 + (l>>4)*8 + j]);
  return f;
}
template<bool USE_WS>
__device__ __forceinline__ bf16x8 get_ba(const bf16x8* wsf, const float* Wa,
                                         int nt, int ks, int l){
  if constexpr (USE_WS) return wsf[3072 + (nt*2 + ks)*64 + l];
  const int col = nt*16 + (l&15);
  bf16x8 f;
  #pragma unroll
  for (int j = 0; j < 8; ++j) f[j] = f2bf(Wa[(ks*32 + (l>>4)*8 + j)*256 + col]);
  return f;
}
}

// ---- pre-kernel: pack Wd/Wc/Wa into bf16 MFMA B-fragment tables in ws ----
__global__ __launch_bounds__(256)
void pack_frags(const float* __restrict__ Wd, const float* __restrict__ Wc,
                const float* __restrict__ Wa, bf16x8* __restrict__ wsf)
{
  const int e  = blockIdx.x*256 + threadIdx.x;      // 0..5119
  const int l  = e & 63;
  const int fi = e >> 6;                            // 0..79
  bf16x8 f;
  if (fi < 32) {                                    // Bd: nt(4) x ks(8)
    const int nt = fi >> 3, ks = fi & 7;
    #pragma unroll
    for (int j = 0; j < 8; ++j) f[j] = f2bf(Wd[(ks*32 + (l>>4)*8 + j)*64 + nt*16 + (l&15)]);
  } else if (fi < 48) {                             // Bc: nt(8) x ks(2)
    const int idx = fi - 32, nt = idx >> 1, ks = idx & 1;
    const int col = nt*16 + (l&15), cw = col>>6, co = col&63;
    #pragma unroll
    for (int j = 0; j < 8; ++j) f[j] = f2bf(Wc[co*128 + cw*64 + ks*32 + (l>>4)*8 + j]);
  } else {                                          // Ba: nt(16) x ks(2)
    const int idx = fi - 48, nt = idx >> 1, ks = idx & 1;
    const int col = nt*16 + (l&15);
    #pragma unroll
    for (int j = 0; j < 8; ++j) f[j] = f2bf(Wa[(ks*32 + (l>>4)*8 + j)*256 + col]);
  }
  wsf[e] = f;
}

template<bool USE_WS>
__global__ __launch_bounds__(1024)
void fused_gnn_v7(const float* __restrict__ x,
                  const float* __restrict__ Wd, const float* __restrict__ bd,
                  const float* __restrict__ bn1s, const float* __restrict__ bn1b,
                  const float* __restrict__ bn1m, const float* __restrict__ bn1v,
                  const float* __restrict__ Wc,
                  const float* __restrict__ bn2s, const float* __restrict__ bn2b,
                  const float* __restrict__ bn2m, const float* __restrict__ bn2v,
                  const float* __restrict__ Wa, const float* __restrict__ ba,
                  const bf16x8* __restrict__ wsf,
                  float* __restrict__ out)
{
  // static shared, 63.0 KB total -> two 1024-thread blocks per CU
  __shared__ short xbf[80*XBSTR];                   // 42240 B (rows 68-79: MFMA tail garbage)
  __shared__ __align__(16) char uni_raw[10560];     // union: xd bf16[68][68] | mw f32[20][132] | att bf16[20][264]
  __shared__ short mbf[32*MSTR];                    // 4608 B (rows 20-31 garbage)
  __shared__ short abf[32*MSTR];                    // 4608 B
  __shared__ float a1c[64], b1c[64], a2c[64], b2c[64];

  short* xd  = (short*)uni_raw;
  float* mw  = (float*)uni_raw;
  short* att = (short*)uni_raw;

  const int tid  = threadIdx.x;
  const int l    = tid & 63;
  const int wv   = tid >> 6;            // wave 0..15
  const int arow = l & 15;
  const int ak8  = (l >> 4) * 8;

  // ---- one-time: fold BN affines (b_down folded into bn1 bias) ----
  if (tid < 64) {
    float av = bn1s[tid] * rsqrtf(bn1v[tid] + 1e-5f);
    a1c[tid] = av; b1c[tid] = (bd[tid] - bn1m[tid])*av + bn1b[tid];
    float av2 = bn2s[tid] * rsqrtf(bn2v[tid] + 1e-5f);
    a2c[tid] = av2; b2c[tid] = bn2b[tid] - bn2m[tid]*av2;
  }

  // ---- persistent weight fragments: Bd (32 VGPR) + Bc (8 VGPR) ----
  const int ntA  = wv & 3;               // phase A n-tile
  const int colA = ntA*16 + arow;
  bf16x8 Bd[8];
  #pragma unroll
  for (int ks = 0; ks < 8; ++ks) Bd[ks] = get_bd<USE_WS>(wsf, Wd, ntA, ks, l);
  const int ntC  = wv & 7;               // phase B2 n-tile (N=128)
  const int colC = ntC*16 + arow;
  bf16x8 Bc[2];
  #pragma unroll
  for (int ks = 0; ks < 2; ++ks) Bc[ks] = get_bc<USE_WS>(wsf, Wc, ntC, ks, l);
  const int colE = wv*16 + arow;         // phase E n-tile (N=256); Ba loaded per-iter
  const float bav = ba[colE];

  // ---- T14 prefetch: first 4-batch group (4352 float4 / 1024 threads) ----
  const v4f* x4 = (const v4f*)x;
  v4f xr0, xr1, xr2, xr3, xr4;
  {
    const size_t b4 = (size_t)(blockIdx.x*NB) * 1088;
    xr0 = x4[b4 + tid];        xr1 = x4[b4 + 1024 + tid];
    xr2 = x4[b4 + 2048 + tid]; xr3 = x4[b4 + 3072 + tid];
    if (tid < 256) xr4 = x4[b4 + 4096 + tid];
  }

  for (int it = 0; it < NIT; ++it) {
    // ---- stage regs -> bf16 LDS (one conversion per element) ----
    {
      auto store4 = [&](v4f v, int e){
        const int r = e >> 6, c4 = (e & 63) * 4;
        bf16x4 b; b[0]=f2bf(v.x); b[1]=f2bf(v.y); b[2]=f2bf(v.z); b[3]=f2bf(v.w);
        *(bf16x4*)&xbf[r*XBSTR + c4] = b;
      };
      store4(xr0, tid);        store4(xr1, 1024 + tid);
      store4(xr2, 2048 + tid); store4(xr3, 3072 + tid);
      if (tid < 256) store4(xr4, 4096 + tid);
    }
    // issue next group's loads (overlap with this iteration's compute)
    if (it + 1 < NIT) {
      const size_t b4 = (size_t)(blockIdx.x*NB + (it+1)*4) * 1088;
      xr0 = x4[b4 + tid];        xr1 = x4[b4 + 1024 + tid];
      xr2 = x4[b4 + 2048 + tid]; xr3 = x4[b4 + 3072 + tid];
      if (tid < 256) xr4 = x4[b4 + 4096 + tid];
    }
    __syncthreads();                                   // 1: stage -> A

    // ---- Phase A (MFMA): xd = silu(bn1(x @ Wd)), M=68, N=64, K=256 ----
    {
      const int mt = wv >> 2;                          // m-tile 0..3 (rows 0..63)
      f32x4 acc0 = {0.f,0.f,0.f,0.f};
      #pragma unroll
      for (int ks = 0; ks < 8; ++ks) {
        bf16x8 a0 = *(const bf16x8*)&xbf[(mt*16 + arow)*XBSTR + ks*32 + ak8];
        acc0 = __builtin_amdgcn_mfma_f32_16x16x32_bf16(a0, Bd[ks], acc0, 0, 0, 0);
      }
      f32x4 acc1 = {0.f,0.f,0.f,0.f};
      if (wv < 4) {                                    // tail tile rows 64..79 (68-79 garbage)
        #pragma unroll
        for (int ks = 0; ks < 8; ++ks) {
          bf16x8 a1 = *(const bf16x8*)&xbf[(64 + arow)*XBSTR + ks*32 + ak8];
          acc1 = __builtin_amdgcn_mfma_f32_16x16x32_bf16(a1, Bd[ks], acc1, 0, 0, 0);
        }
      }
      const float av = a1c[colA], bv = b1c[colA];
      #pragma unroll
      for (int j = 0; j < 4; ++j) {
        const int r = mt*16 + (l>>4)*4 + j;            // <= 63
        xd[r*XDSTR + colA] = f2bf(fsilu(acc0[j]*av + bv));
      }
      if (wv < 4) {
        #pragma unroll
        for (int j = 0; j < 4; ++j) {
          const int r = 64 + (l>>4)*4 + j;
          if (r < 68) xd[r*XDSTR + colA] = f2bf(fsilu(acc1[j]*av + bv));
        }
      }
    }
    __syncthreads();                                   // 2: A -> B1

    // ---- Phase B1: group means -> bf16 (rows qg = q*5+g, 20 total) ----
    #pragma unroll
    for (int pass = 0; pass < 2; ++pass) {
      const int u = pass*1024 + tid;
      if (u < 1280) {
        const int qg = u >> 6, i = u & 63;
        const int q = qg / 5, g = qg - q*5;
        const int rb = q*17;
        float m;
        if (g == 0) {
          m = (bf2f(xd[(rb+0)*XDSTR+i])+bf2f(xd[(rb+1)*XDSTR+i])+bf2f(xd[(rb+2)*XDSTR+i])
              +bf2f(xd[(rb+3)*XDSTR+i])+bf2f(xd[(rb+4)*XDSTR+i]))*0.2f;
        } else {
          const int kb = rb + ((g==1)?5:(g==2)?6:(g==3)?11:12);
          m = (bf2f(xd[kb*XDSTR+i]) + bf2f(xd[(kb+2)*XDSTR+i]) + bf2f(xd[(kb+4)*XDSTR+i]))*(1.f/3.f);
        }
        mbf[qg*MSTR + i] = f2bf(m);
      }
    }
    __syncthreads();                                   // 3: B1 -> B2

    // ---- Phase B2 (MFMA): mw = means @ [Wc1|Wc2], M=20, N=128, K=64 ----
    {
      const int mt = wv >> 3;                          // 0..1
      f32x4 acc = {0.f,0.f,0.f,0.f};
      #pragma unroll
      for (int ks = 0; ks < 2; ++ks) {
        bf16x8 a = *(const bf16x8*)&mbf[(mt*16 + arow)*MSTR + ks*32 + ak8];
        acc = __builtin_amdgcn_mfma_f32_16x16x32_bf16(a, Bc[ks], acc, 0, 0, 0);
      }
      #pragma unroll
      for (int j = 0; j < 4; ++j) {
        const int qg = mt*16 + (l>>4)*4 + j;
        if (qg < 20) mw[qg*MWSTR + colC] = acc[j];
      }
    }
    __syncthreads();                                   // 4: B2 -> B3

    // transient phase-E weight frags; issued here so B3 covers the load latency
    bf16x8 BaT[2];
    #pragma unroll
    for (int ks = 0; ks < 2; ++ks) BaT[ks] = get_ba<USE_WS>(wsf, Wa, wv, ks, l);

    // ---- Phase B3: agg[qg][o] = sum_{cc!=g} silu(bn2(mw1-mw2[g]+mw2[cc])) ----
    #pragma unroll
    for (int pass = 0; pass < 2; ++pass) {
      const int u = pass*1024 + tid;
      if (u < 1280) {
        const int qg = u >> 6, o = u & 63;
        const int q = qg / 5, g = qg - q*5;
        const float bse = mw[qg*MWSTR + o] - mw[qg*MWSTR + 64 + o];
        const float av = a2c[o], bv = b2c[o];
        float s = 0.f;
        #pragma unroll
        for (int cc = 0; cc < 5; ++cc) {
          if (cc != g) s += fsilu((bse + mw[(q*5+cc)*MWSTR + 64 + o])*av + bv);
        }
        abf[qg*MSTR + o] = f2bf(s);
      }
    }
    __syncthreads();                                   // 5: B3 -> E

    // ---- Phase E (MFMA): att = sigmoid(agg @ Wa + ba), M=20, N=256, K=64 ----
    {
      f32x4 accE0 = {0.f,0.f,0.f,0.f}, accE1 = {0.f,0.f,0.f,0.f};
      #pragma unroll
      for (int ks = 0; ks < 2; ++ks) {
        bf16x8 a0 = *(const bf16x8*)&abf[(arow)*MSTR      + ks*32 + ak8];
        bf16x8 a1 = *(const bf16x8*)&abf[(16 + arow)*MSTR + ks*32 + ak8];
        accE0 = __builtin_amdgcn_mfma_f32_16x16x32_bf16(a0, BaT[ks], accE0, 0, 0, 0);
        accE1 = __builtin_amdgcn_mfma_f32_16x16x32_bf16(a1, BaT[ks], accE1, 0, 0, 0);
      }
      #pragma unroll
      for (int j = 0; j < 4; ++j) {
        const int qg0 = (l>>4)*4 + j;                  // 0..15
        att[qg0*ASTR + colE] = f2bf(fsigm(accE0[j] + bav));
        const int qg1 = 16 + (l>>4)*4 + j;
        if (qg1 < 20) att[qg1*ASTR + colE] = f2bf(fsigm(accE1[j] + bav));
      }
    }
    __syncthreads();                                   // 6: E -> F

    // ---- Phase F: out[k][c] = bf16(x)[k][c] * att[q*5+GOF[k]][c] ----
    {
      const int q = tid >> 8, c = tid & 255;
      float a5[5];
      #pragma unroll
      for (int g = 0; g < 5; ++g) a5[g] = bf2f(att[(q*5+g)*ASTR + c]);
      const size_t batch = (size_t)blockIdx.x*NB + it*4 + q;
      float* og = out + batch*4352 + c;
      const int xr = q*17;
      constexpr int GOF[17] = {0,0,0,0,0,1,2,1,2,1,2,3,4,3,4,3,4};
      #pragma unroll
      for (int k = 0; k < 17; ++k)
        og[k*256] = bf2f(xbf[(xr+k)*XBSTR + c]) * a5[GOF[k]];
    }
    __syncthreads();                                   // 7: F -> next stage
  }
}

extern "C" void kernel_launch(void* const* d_in, const int* in_sizes, int n_in,
                              void* d_out, int out_size, void* d_ws, size_t ws_size,
                              hipStream_t stream) {
    (void)n_in; (void)out_size;
    const float* x   = (const float*)d_in[0];
    const float* Wd  = (const float*)d_in[1];
    const float* bd  = (const float*)d_in[2];
    const float* s1  = (const float*)d_in[3];
    const float* b1  = (const float*)d_in[4];
    const float* m1  = (const float*)d_in[5];
    const float* v1  = (const float*)d_in[6];
    const float* Wc  = (const float*)d_in[7];
    const float* s2  = (const float*)d_in[8];
    const float* b2  = (const float*)d_in[9];
    const float* m2  = (const float*)d_in[10];
    const float* v2  = (const float*)d_in[11];
    const float* Wa  = (const float*)d_in[12];
    const float* ba  = (const float*)d_in[13];

    const int Btot = in_sizes[0] / (17 * 256);   // 4096
    const int GRID = Btot / NB;                  // 512 blocks -> 2 per CU, all resident
    bf16x8* wsf = (bf16x8*)d_ws;

    if (ws_size >= (size_t)FRAG_SLOTS * 16) {
        pack_frags<<<FRAG_SLOTS/256, 256, 0, stream>>>(Wd, Wc, Wa, wsf);
        fused_gnn_v7<true><<<GRID, 1024, 0, stream>>>(
            x, Wd, bd, s1, b1, m1, v1, Wc, s2, b2, m2, v2, Wa, ba,
            wsf, (float*)d_out);
    } else {
        fused_gnn_v7<false><<<GRID, 1024, 0, stream>>>(
            x, Wd, bd, s1, b1, m1, v1, Wc, s2, b2, m2, v2, Wa, ba,
            wsf, (float*)d_out);
    }
}

// Round 9
// 49.934 us; speedup vs baseline: 1.0605x; 1.0605x over previous
//
#include <hip/hip_runtime.h>

typedef float  v4f    __attribute__((ext_vector_type(4)));
typedef float  f32x4  __attribute__((ext_vector_type(4)));
typedef short  bf16x8 __attribute__((ext_vector_type(8)));
typedef short  bf16x4 __attribute__((ext_vector_type(4)));

namespace {
constexpr int XBSTR = 264;   // xbf row stride (bf16); 528 B, 16B-multiple
constexpr int XDSTR = 68;    // xd row stride (bf16)
constexpr int MWSTR = 132;   // mw row stride (f32)
constexpr int ASTR  = 264;   // att row stride (bf16)
constexpr int MSTR  = 72;    // mbf/abf row stride (bf16); 144 B, 16B-multiple
constexpr int FRAG_SLOTS = 5120;

__device__ __forceinline__ float fsilu(float v){ return v/(1.f+__expf(-v)); }
__device__ __forceinline__ float fsigm(float v){ return 1.f/(1.f+__expf(-v)); }
__device__ __forceinline__ short f2bf(float f){          // fp32 -> bf16 RNE
  unsigned u = __builtin_bit_cast(unsigned, f);
  return (short)((u + 0x7FFFu + ((u>>16)&1u)) >> 16);
}
__device__ __forceinline__ float bf2f(short s){
  unsigned u = ((unsigned)(unsigned short)s) << 16;
  return __builtin_bit_cast(float, u);
}

// ---- B-fragment getters: frag table in ws (fast) or on-the-fly (fallback) ----
template<bool USE_WS>
__device__ __forceinline__ bf16x8 get_bd(const bf16x8* wsf, const float* Wd,
                                         int nt, int ks, int l){
  if constexpr (USE_WS) return wsf[(nt*8 + ks)*64 + l];
  bf16x8 f;
  #pragma unroll
  for (int j = 0; j < 8; ++j) f[j] = f2bf(Wd[(ks*32 + (l>>4)*8 + j)*64 + nt*16 + (l&15)]);
  return f;
}
template<bool USE_WS>
__device__ __forceinline__ bf16x8 get_bc(const bf16x8* wsf, const float* Wc,
                                         int nt, int ks, int l){
  if constexpr (USE_WS) return wsf[2048 + (nt*2 + ks)*64 + l];
  const int col = nt*16 + (l&15), cw = col>>6, co = col&63;
  bf16x8 f;
  #pragma unroll
  for (int j = 0; j < 8; ++j) f[j] = f2bf(Wc[co*128 + cw*64 + ks*32 + (l>>4)*8 + j]);
  return f;
}
template<bool USE_WS>
__device__ __forceinline__ bf16x8 get_ba(const bf16x8* wsf, const float* Wa,
                                         int nt, int ks, int l){
  if constexpr (USE_WS) return wsf[3072 + (nt*2 + ks)*64 + l];
  const int col = nt*16 + (l&15);
  bf16x8 f;
  #pragma unroll
  for (int j = 0; j < 8; ++j) f[j] = f2bf(Wa[(ks*32 + (l>>4)*8 + j)*256 + col]);
  return f;
}
}

// ---- pre-kernel: pack Wd/Wc/Wa into bf16 MFMA B-fragment tables in ws ----
__global__ __launch_bounds__(256)
void pack_frags(const float* __restrict__ Wd, const float* __restrict__ Wc,
                const float* __restrict__ Wa, bf16x8* __restrict__ wsf)
{
  const int e  = blockIdx.x*256 + threadIdx.x;      // 0..5119
  const int l  = e & 63;
  const int fi = e >> 6;                            // 0..79
  bf16x8 f;
  if (fi < 32) {                                    // Bd: nt(4) x ks(8)
    const int nt = fi >> 3, ks = fi & 7;
    #pragma unroll
    for (int j = 0; j < 8; ++j) f[j] = f2bf(Wd[(ks*32 + (l>>4)*8 + j)*64 + nt*16 + (l&15)]);
  } else if (fi < 48) {                             // Bc: nt(8) x ks(2)
    const int idx = fi - 32, nt = idx >> 1, ks = idx & 1;
    const int col = nt*16 + (l&15), cw = col>>6, co = col&63;
    #pragma unroll
    for (int j = 0; j < 8; ++j) f[j] = f2bf(Wc[co*128 + cw*64 + ks*32 + (l>>4)*8 + j]);
  } else {                                          // Ba: nt(16) x ks(2)
    const int idx = fi - 48, nt = idx >> 1, ks = idx & 1;
    const int col = nt*16 + (l&15);
    #pragma unroll
    for (int j = 0; j < 8; ++j) f[j] = f2bf(Wa[(ks*32 + (l>>4)*8 + j)*256 + col]);
  }
  wsf[e] = f;
}

template<bool USE_WS>
__global__ __launch_bounds__(256, 8)
void fused_gnn_v8(const float* __restrict__ x,
                  const float* __restrict__ Wd, const float* __restrict__ bd,
                  const float* __restrict__ bn1s, const float* __restrict__ bn1b,
                  const float* __restrict__ bn1m, const float* __restrict__ bn1v,
                  const float* __restrict__ Wc,
                  const float* __restrict__ bn2s, const float* __restrict__ bn2b,
                  const float* __restrict__ bn2m, const float* __restrict__ bn2v,
                  const float* __restrict__ Wa, const float* __restrict__ ba,
                  const bf16x8* __restrict__ wsf,
                  float* __restrict__ out)
{
  // 20,088 B static LDS -> up to 8 blocks/CU (8 x 20.5KB = 160KB)
  __shared__ short xbf[18*XBSTR];                   // 9504 B; row 17 = tail-clamp target (garbage OK)
  __shared__ __align__(16) char uni_raw[5*ASTR*2];  // 2640 B union: xd bf16[17][68] | att bf16[5][264]
  __shared__ float mw[5*MWSTR];                     // 2640 B
  __shared__ short mbf[16*MSTR];                    // 2304 B (rows 5-15 garbage, discarded MFMA rows)
  __shared__ short abf[16*MSTR];                    // 2304 B
  __shared__ float a1c[64], b1c[64], a2c[64], b2c[64];

  short* xd  = (short*)uni_raw;
  short* att = (short*)uni_raw;

  const int tid  = threadIdx.x;
  const int l    = tid & 63;
  const int wv   = tid >> 6;            // wave 0..3
  const int arow = l & 15;
  const int ak8  = (l >> 4) * 8;
  const int b    = blockIdx.x;          // one batch per block

  // ---- fold BN affines (b_down folded into bn1 bias); visible after barrier 1 ----
  if (tid < 64) {
    float av = bn1s[tid] * rsqrtf(bn1v[tid] + 1e-5f);
    a1c[tid] = av; b1c[tid] = (bd[tid] - bn1m[tid])*av + bn1b[tid];
    float av2 = bn2s[tid] * rsqrtf(bn2v[tid] + 1e-5f);
    a2c[tid] = av2; b2c[tid] = bn2b[tid] - bn2m[tid]*av2;
  }

  // ---- stage x -> bf16 LDS (coalesced float4, 4.25 per thread) ----
  {
    const v4f* x4 = (const v4f*)(x + (size_t)b * 4352);
    #pragma unroll
    for (int i = 0; i < 5; ++i) {
      const int idx = i*256 + tid;
      if (idx < 1088) {
        const v4f v = x4[idx];
        const int r = idx >> 6, c4 = (idx & 63) * 4;
        bf16x4 bb; bb[0]=f2bf(v.x); bb[1]=f2bf(v.y); bb[2]=f2bf(v.z); bb[3]=f2bf(v.w);
        *(bf16x4*)&xbf[r*XBSTR + c4] = bb;
      }
    }
  }
  __syncthreads();                                   // barrier 1: stage(+BN) -> A

  // ---- Phase A (MFMA): xd = silu(bn1(x @ Wd)), M=17, N=64, K=256 ----
  // wave wv owns n-tile wv. Bd loaded in two halves of 4 (16 VGPR live).
  {
    f32x4 acc0 = {0.f,0.f,0.f,0.f};                  // rows 0..15
    f32x4 acc1 = {0.f,0.f,0.f,0.f};                  // tail tile: row 0 = batch row 16
    const int rowT = (arow == 0) ? 16 : 17;          // tail rows 1..15 read garbage row 17, discarded
    #pragma unroll
    for (int h = 0; h < 2; ++h) {
      bf16x8 Bd[4];
      #pragma unroll
      for (int k4 = 0; k4 < 4; ++k4) Bd[k4] = get_bd<USE_WS>(wsf, Wd, wv, h*4 + k4, l);
      #pragma unroll
      for (int k4 = 0; k4 < 4; ++k4) {
        const int ks = h*4 + k4;
        bf16x8 a0 = *(const bf16x8*)&xbf[arow*XBSTR + ks*32 + ak8];
        acc0 = __builtin_amdgcn_mfma_f32_16x16x32_bf16(a0, Bd[k4], acc0, 0, 0, 0);
        bf16x8 a1 = *(const bf16x8*)&xbf[rowT*XBSTR + ks*32 + ak8];
        acc1 = __builtin_amdgcn_mfma_f32_16x16x32_bf16(a1, Bd[k4], acc1, 0, 0, 0);
      }
    }
    const int colA = wv*16 + arow;
    const float av = a1c[colA], bv = b1c[colA];
    #pragma unroll
    for (int j = 0; j < 4; ++j) {
      const int r = (l>>4)*4 + j;                    // 0..15
      xd[r*XDSTR + colA] = f2bf(fsilu(acc0[j]*av + bv));
    }
    if ((l >> 4) == 0)
      xd[16*XDSTR + colA] = f2bf(fsilu(acc1[0]*av + bv));
  }
  __syncthreads();                                   // barrier 2: A -> B1

  // ---- Phase B1: group means (redundant per wave, identical bits) ----
  {
    const int i = l;
    float m0 = (bf2f(xd[0*XDSTR+i])+bf2f(xd[1*XDSTR+i])+bf2f(xd[2*XDSTR+i])
               +bf2f(xd[3*XDSTR+i])+bf2f(xd[4*XDSTR+i]))*0.2f;
    mbf[0*MSTR + i] = f2bf(m0);
    #pragma unroll
    for (int g = 1; g < 5; ++g) {
      const int kb = (g==1)?5:(g==2)?6:(g==3)?11:12;
      float m = (bf2f(xd[kb*XDSTR+i]) + bf2f(xd[(kb+2)*XDSTR+i])
               + bf2f(xd[(kb+4)*XDSTR+i]))*(1.f/3.f);
      mbf[g*MSTR + i] = f2bf(m);
    }
  }
  // no barrier: B2 reads mbf columns written by this wave (compiler orders via lgkmcnt)

  // ---- Phase B2 (MFMA): mw = means @ [Wc1|Wc2], M=5, N=128, wave owns 2 n-tiles ----
  {
    bf16x8 am[2];
    #pragma unroll
    for (int ks = 0; ks < 2; ++ks)
      am[ks] = *(const bf16x8*)&mbf[arow*MSTR + ks*32 + ak8];
    #pragma unroll
    for (int t = 0; t < 2; ++t) {
      const int nt = wv*2 + t;
      f32x4 acc = {0.f,0.f,0.f,0.f};
      #pragma unroll
      for (int ks = 0; ks < 2; ++ks)
        acc = __builtin_amdgcn_mfma_f32_16x16x32_bf16(
                am[ks], get_bc<USE_WS>(wsf, Wc, nt, ks, l), acc, 0, 0, 0);
      #pragma unroll
      for (int j = 0; j < 4; ++j) {
        const int g = (l>>4)*4 + j;
        if (g < 5) mw[g*MWSTR + nt*16 + arow] = acc[j];
      }
    }
  }
  __syncthreads();                                   // barrier 3: B2 -> B3 (also orders xd-reads vs att-writes)

  // ---- Phase B3: agg (redundant per wave) ----
  {
    const int o = l;
    const float av = a2c[o], bv = b2c[o];
    float m2c[5];
    #pragma unroll
    for (int cc = 0; cc < 5; ++cc) m2c[cc] = mw[cc*MWSTR + 64 + o];
    #pragma unroll
    for (int g = 0; g < 5; ++g) {
      const float bse = mw[g*MWSTR + o] - m2c[g];
      float s = 0.f;
      #pragma unroll
      for (int cc = 0; cc < 5; ++cc) {
        if (cc != g) s += fsilu((bse + m2c[cc])*av + bv);
      }
      abf[g*MSTR + o] = f2bf(s);
    }
  }
  // no barrier: E reads abf written by this wave

  // ---- Phase E (MFMA): att = sigmoid(agg @ Wa + ba), M=5, N=256, wave owns 4 n-tiles ----
  {
    bf16x8 ae[2];
    #pragma unroll
    for (int ks = 0; ks < 2; ++ks)
      ae[ks] = *(const bf16x8*)&abf[arow*MSTR + ks*32 + ak8];
    #pragma unroll
    for (int t = 0; t < 4; ++t) {
      const int nt = wv*4 + t;
      const int colE = nt*16 + arow;
      f32x4 acc = {0.f,0.f,0.f,0.f};
      #pragma unroll
      for (int ks = 0; ks < 2; ++ks)
        acc = __builtin_amdgcn_mfma_f32_16x16x32_bf16(
                ae[ks], get_ba<USE_WS>(wsf, Wa, nt, ks, l), acc, 0, 0, 0);
      const float bav = ba[colE];
      #pragma unroll
      for (int j = 0; j < 4; ++j) {
        const int g = (l>>4)*4 + j;
        if (g < 5) att[g*ASTR + colE] = f2bf(fsigm(acc[j] + bav));
      }
    }
  }
  __syncthreads();                                   // barrier 4: E -> F

  // ---- Phase F: out[k][c] = bf16(x)[k][c] * att[GOF[k]][c] ----
  {
    const int c = tid;
    float a5[5];
    #pragma unroll
    for (int g = 0; g < 5; ++g) a5[g] = bf2f(att[g*ASTR + c]);
    float* og = out + (size_t)b*4352 + c;
    constexpr int GOF[17] = {0,0,0,0,0,1,2,1,2,1,2,3,4,3,4,3,4};
    #pragma unroll
    for (int k = 0; k < 17; ++k)
      og[k*256] = bf2f(xbf[k*XBSTR + c]) * a5[GOF[k]];
  }
}

extern "C" void kernel_launch(void* const* d_in, const int* in_sizes, int n_in,
                              void* d_out, int out_size, void* d_ws, size_t ws_size,
                              hipStream_t stream) {
    (void)n_in; (void)out_size;
    const float* x   = (const float*)d_in[0];
    const float* Wd  = (const float*)d_in[1];
    const float* bd  = (const float*)d_in[2];
    const float* s1  = (const float*)d_in[3];
    const float* b1  = (const float*)d_in[4];
    const float* m1  = (const float*)d_in[5];
    const float* v1  = (const float*)d_in[6];
    const float* Wc  = (const float*)d_in[7];
    const float* s2  = (const float*)d_in[8];
    const float* b2  = (const float*)d_in[9];
    const float* m2  = (const float*)d_in[10];
    const float* v2  = (const float*)d_in[11];
    const float* Wa  = (const float*)d_in[12];
    const float* ba  = (const float*)d_in[13];

    const int Btot = in_sizes[0] / (17 * 256);   // 4096 -> one block per batch
    bf16x8* wsf = (bf16x8*)d_ws;

    if (ws_size >= (size_t)FRAG_SLOTS * 16) {
        pack_frags<<<FRAG_SLOTS/256, 256, 0, stream>>>(Wd, Wc, Wa, wsf);
        fused_gnn_v8<true><<<Btot, 256, 0, stream>>>(
            x, Wd, bd, s1, b1, m1, v1, Wc, s2, b2, m2, v2, Wa, ba,
            wsf, (float*)d_out);
    } else {
        fused_gnn_v8<false><<<Btot, 256, 0, stream>>>(
            x, Wd, bd, s1, b1, m1, v1, Wc, s2, b2, m2, v2, Wa, ba,
            wsf, (float*)d_out);
    }
}

// Round 11
// 46.922 us; speedup vs baseline: 1.1285x; 1.0642x over previous
//
#include <hip/hip_runtime.h>

typedef float  v4f    __attribute__((ext_vector_type(4)));
typedef float  f32x4  __attribute__((ext_vector_type(4)));
typedef short  bf16x8 __attribute__((ext_vector_type(8)));

namespace {
constexpr int XBSTR = 264;   // xbf row stride (shorts); 528 B = 33x16 (b128-aligned rows, bank offset 4/row)
constexpr int XDT   = 24;    // xdT row stride (shorts); 48 B (b128-aligned rows)
constexpr int MWC   = 129;   // mw row stride (f32)
constexpr int ATS   = 258;   // att row stride (shorts)
constexpr int MSTR  = 72;    // mbf/abf row stride (shorts); 144 B
constexpr int FRAG_SLOTS = 5120;

__device__ __forceinline__ float fsilu(float v){ return v/(1.f+__expf(-v)); }
__device__ __forceinline__ float fsigm(float v){ return 1.f/(1.f+__expf(-v)); }

// fp32 pair -> packed bf16x2 via the HW instruction (1 VALU op / 2 elems)
__device__ __forceinline__ unsigned f2bf2(float a, float b){
  unsigned r;
  asm("v_cvt_pk_bf16_f32 %0, %1, %2" : "=v"(r) : "v"(a), "v"(b));
  return r;
}
__device__ __forceinline__ short f2bf(float f){   // scalar: RNE, matches cvt_pk
  unsigned u = __builtin_bit_cast(unsigned, f);
  return (short)((u + 0x7FFFu + ((u>>16)&1u)) >> 16);
}
__device__ __forceinline__ float bf2f(short s){
  unsigned u = ((unsigned)(unsigned short)s) << 16;
  return __builtin_bit_cast(float, u);
}

// ---- B-fragment getters: frag table in ws (fast) or on-the-fly (fallback) ----
template<bool USE_WS>
__device__ __forceinline__ bf16x8 get_bd(const bf16x8* wsf, const float* Wd,
                                         int nt, int ks, int l){
  if constexpr (USE_WS) return wsf[(nt*8 + ks)*64 + l];
  bf16x8 f;
  #pragma unroll
  for (int j = 0; j < 8; ++j) f[j] = f2bf(Wd[(ks*32 + (l>>4)*8 + j)*64 + nt*16 + (l&15)]);
  return f;
}
template<bool USE_WS>
__device__ __forceinline__ bf16x8 get_bc(const bf16x8* wsf, const float* Wc,
                                         int nt, int ks, int l){
  if constexpr (USE_WS) return wsf[2048 + (nt*2 + ks)*64 + l];
  const int col = nt*16 + (l&15), cw = col>>6, co = col&63;
  bf16x8 f;
  #pragma unroll
  for (int j = 0; j < 8; ++j) f[j] = f2bf(Wc[co*128 + cw*64 + ks*32 + (l>>4)*8 + j]);
  return f;
}
template<bool USE_WS>
__device__ __forceinline__ bf16x8 get_ba(const bf16x8* wsf, const float* Wa,
                                         int nt, int ks, int l){
  if constexpr (USE_WS) return wsf[3072 + (nt*2 + ks)*64 + l];
  const int col = nt*16 + (l&15);
  bf16x8 f;
  #pragma unroll
  for (int j = 0; j < 8; ++j) f[j] = f2bf(Wa[(ks*32 + (l>>4)*8 + j)*256 + col]);
  return f;
}
}

// ---- pre-kernel: pack Wd/Wc/Wa into bf16 MFMA B-fragment tables in ws ----
__global__ __launch_bounds__(256)
void pack_frags(const float* __restrict__ Wd, const float* __restrict__ Wc,
                const float* __restrict__ Wa, bf16x8* __restrict__ wsf)
{
  const int e  = blockIdx.x*256 + threadIdx.x;      // 0..5119
  const int l  = e & 63;
  const int fi = e >> 6;                            // 0..79
  bf16x8 f;
  if (fi < 32) {                                    // Bd: nt(4) x ks(8)
    const int nt = fi >> 3, ks = fi & 7;
    #pragma unroll
    for (int j = 0; j < 8; ++j) f[j] = f2bf(Wd[(ks*32 + (l>>4)*8 + j)*64 + nt*16 + (l&15)]);
  } else if (fi < 48) {                             // Bc: nt(8) x ks(2)
    const int idx = fi - 32, nt = idx >> 1, ks = idx & 1;
    const int col = nt*16 + (l&15), cw = col>>6, co = col&63;
    #pragma unroll
    for (int j = 0; j < 8; ++j) f[j] = f2bf(Wc[co*128 + cw*64 + ks*32 + (l>>4)*8 + j]);
  } else {                                          // Ba: nt(16) x ks(2)
    const int idx = fi - 48, nt = idx >> 1, ks = idx & 1;
    const int col = nt*16 + (l&15);
    #pragma unroll
    for (int j = 0; j < 8; ++j) f[j] = f2bf(Wa[(ks*32 + (l>>4)*8 + j)*256 + col]);
  }
  wsf[e] = f;
}

template<bool USE_WS>
__global__ __launch_bounds__(256, 8)
void fused_gnn_v9(const float* __restrict__ x,
                  const float* __restrict__ Wd, const float* __restrict__ bd,
                  const float* __restrict__ bn1s, const float* __restrict__ bn1b,
                  const float* __restrict__ bn1m, const float* __restrict__ bn1v,
                  const float* __restrict__ Wc,
                  const float* __restrict__ bn2s, const float* __restrict__ bn2b,
                  const float* __restrict__ bn2m, const float* __restrict__ bn2v,
                  const float* __restrict__ Wa, const float* __restrict__ ba,
                  const bf16x8* __restrict__ wsf,
                  float* __restrict__ out)
{
  // ~19.8 KB static LDS
  __shared__ short xbf[18*XBSTR];                   // 9504 B; row 17 = tail-clamp garbage target
  __shared__ __align__(16) char uni_raw[3072];      // union: xdT bf16[64][24] | att bf16[5][258]
  __shared__ float mw[5*MWC];                       // 2580 B
  __shared__ short mbf[16*MSTR];                    // 2304 B (rows 5-15 garbage)
  __shared__ short abf[16*MSTR];                    // 2304 B

  short* xdT = (short*)uni_raw;   // dead after B1 (barrier 3 separates from att writes)
  short* att = (short*)uni_raw;

  const int tid  = threadIdx.x;
  const int l    = tid & 63;
  const int wv   = tid >> 6;            // wave 0..3
  const int arow = l & 15;
  const int ak8  = (l >> 4) * 8;
  const int b    = blockIdx.x;          // one batch per block
  const int colA = wv*16 + arow;

  // ---- per-lane BN affines in registers (b_down folded into bn1 bias) ----
  const float a1r = bn1s[colA] * rsqrtf(bn1v[colA] + 1e-5f);
  const float b1r = (bd[colA] - bn1m[colA])*a1r + bn1b[colA];
  const float a2r = bn2s[l] * rsqrtf(bn2v[l] + 1e-5f);
  const float b2r = bn2b[l] - bn2m[l]*a2r;

  // ---- stage x -> bf16 LDS via cvt_pk (coalesced float4, 4.25 per thread) ----
  {
    const v4f* x4 = (const v4f*)(x + (size_t)b * 4352);
    #pragma unroll
    for (int i = 0; i < 5; ++i) {
      const int idx = i*256 + tid;
      if (idx < 1088) {
        const v4f v = x4[idx];
        const int r = idx >> 6, c4 = (idx & 63) * 4;
        uint2 u; u.x = f2bf2(v.x, v.y); u.y = f2bf2(v.z, v.w);
        *(uint2*)&xbf[r*XBSTR + c4] = u;
      }
    }
  }
  __syncthreads();                                   // barrier 1: stage -> A

  // ---- Phase A (MFMA): xd = silu(bn1(x @ Wd)), M=17, N=64, K=256; epilogue -> xdT ----
  {
    f32x4 acc0 = {0.f,0.f,0.f,0.f};                  // rows 0..15
    f32x4 acc1 = {0.f,0.f,0.f,0.f};                  // tail tile: row 0 = batch row 16
    const int rowT = (arow == 0) ? 16 : 17;          // tail rows 1..15 read garbage row 17, discarded
    #pragma unroll
    for (int h = 0; h < 2; ++h) {
      bf16x8 Bd[4];
      #pragma unroll
      for (int k4 = 0; k4 < 4; ++k4) Bd[k4] = get_bd<USE_WS>(wsf, Wd, wv, h*4 + k4, l);
      #pragma unroll
      for (int k4 = 0; k4 < 4; ++k4) {
        const int ks = h*4 + k4;
        bf16x8 a0 = *(const bf16x8*)&xbf[arow*XBSTR + ks*32 + ak8];
        acc0 = __builtin_amdgcn_mfma_f32_16x16x32_bf16(a0, Bd[k4], acc0, 0, 0, 0);
        bf16x8 a1 = *(const bf16x8*)&xbf[rowT*XBSTR + ks*32 + ak8];
        acc1 = __builtin_amdgcn_mfma_f32_16x16x32_bf16(a1, Bd[k4], acc1, 0, 0, 0);
      }
    }
    const float s0 = fsilu(acc0[0]*a1r + b1r);
    const float s1 = fsilu(acc0[1]*a1r + b1r);
    const float s2 = fsilu(acc0[2]*a1r + b1r);
    const float s3 = fsilu(acc0[3]*a1r + b1r);
    uint2 u; u.x = f2bf2(s0, s1); u.y = f2bf2(s2, s3);
    *(uint2*)&xdT[colA*XDT + (l>>4)*4] = u;          // rows (l>>4)*4..+3 of column colA
    if ((l >> 4) == 0)
      xdT[colA*XDT + 16] = f2bf(fsilu(acc1[0]*a1r + b1r));
  }
  __syncthreads();                                   // barrier 2: A -> B1 (xdT cross-wave)

  // ---- Phase B1: group means from xdT column l (vector reads; redundant per wave) ----
  {
    const bf16x8 rA = *(const bf16x8*)&xdT[l*XDT];       // rows 0-7
    const bf16x8 rB = *(const bf16x8*)&xdT[l*XDT + 8];   // rows 8-15
    const float x16 = bf2f(xdT[l*XDT + 16]);
    float xv[16];
    #pragma unroll
    for (int k = 0; k < 8; ++k) { xv[k] = bf2f(rA[k]); xv[k+8] = bf2f(rB[k]); }
    const float m0 = (xv[0]+xv[1]+xv[2]+xv[3]+xv[4])*0.2f;
    const float m1 = (xv[5]+xv[7]+xv[9])*(1.f/3.f);
    const float m2 = (xv[6]+xv[8]+xv[10])*(1.f/3.f);
    const float m3 = (xv[11]+xv[13]+xv[15])*(1.f/3.f);
    const float m4 = (xv[12]+xv[14]+x16)*(1.f/3.f);
    unsigned p01 = f2bf2(m0, m1);
    unsigned p23 = f2bf2(m2, m3);
    mbf[0*MSTR + l] = (short)(p01 & 0xFFFFu);
    mbf[1*MSTR + l] = (short)(p01 >> 16);
    mbf[2*MSTR + l] = (short)(p23 & 0xFFFFu);
    mbf[3*MSTR + l] = (short)(p23 >> 16);
    mbf[4*MSTR + l] = f2bf(m4);
  }
  // no barrier: B2 reads mbf written by this wave's own lanes (wave-ordered LDS)

  // ---- Phase B2 (MFMA): mw = means @ [Wc1|Wc2], M=5, N=128, wave owns 2 n-tiles ----
  {
    bf16x8 am[2];
    #pragma unroll
    for (int ks = 0; ks < 2; ++ks)
      am[ks] = *(const bf16x8*)&mbf[arow*MSTR + ks*32 + ak8];
    #pragma unroll
    for (int t = 0; t < 2; ++t) {
      const int nt = wv*2 + t;
      f32x4 acc = {0.f,0.f,0.f,0.f};
      #pragma unroll
      for (int ks = 0; ks < 2; ++ks)
        acc = __builtin_amdgcn_mfma_f32_16x16x32_bf16(
                am[ks], get_bc<USE_WS>(wsf, Wc, nt, ks, l), acc, 0, 0, 0);
      #pragma unroll
      for (int j = 0; j < 4; ++j) {
        const int g = (l>>4)*4 + j;
        if (g < 5) mw[g*MWC + nt*16 + arow] = acc[j];
      }
    }
  }
  __syncthreads();      // barrier 3: B2 -> B3 (mw cross-wave; also xdT-reads vs att-writes)

  // ---- Phase B3: agg (redundant per wave; BN2 params in regs) ----
  {
    float m2c[5];
    #pragma unroll
    for (int cc = 0; cc < 5; ++cc) m2c[cc] = mw[cc*MWC + 64 + l];
    #pragma unroll
    for (int g = 0; g < 5; ++g) {
      const float bse = mw[g*MWC + l] - m2c[g];
      float s = 0.f;
      #pragma unroll
      for (int cc = 0; cc < 5; ++cc) {
        if (cc != g) s += fsilu((bse + m2c[cc])*a2r + b2r);
      }
      abf[g*MSTR + l] = f2bf(s);
    }
  }
  // no barrier: E reads abf written by this wave

  // ---- Phase E (MFMA): att = sigmoid(agg @ Wa + ba), M=5, N=256, wave owns 4 n-tiles ----
  {
    bf16x8 ae[2];
    #pragma unroll
    for (int ks = 0; ks < 2; ++ks)
      ae[ks] = *(const bf16x8*)&abf[arow*MSTR + ks*32 + ak8];
    #pragma unroll
    for (int t = 0; t < 4; ++t) {
      const int nt = wv*4 + t;
      const int colE = nt*16 + arow;
      f32x4 acc = {0.f,0.f,0.f,0.f};
      #pragma unroll
      for (int ks = 0; ks < 2; ++ks)
        acc = __builtin_amdgcn_mfma_f32_16x16x32_bf16(
                ae[ks], get_ba<USE_WS>(wsf, Wa, nt, ks, l), acc, 0, 0, 0);
      const float bav = ba[colE];
      #pragma unroll
      for (int j = 0; j < 4; ++j) {
        const int g = (l>>4)*4 + j;
        if (g < 5) att[g*ATS + colE] = f2bf(fsigm(acc[j] + bav));
      }
    }
  }
  __syncthreads();                                   // barrier 4: E -> F

  // ---- Phase F: out[k][c] = bf16(x)[k][c] * att[GOF[k]][c] ----
  {
    const int c = tid;
    float a5[5];
    #pragma unroll
    for (int g = 0; g < 5; ++g) a5[g] = bf2f(att[g*ATS + c]);
    float* og = out + (size_t)b*4352 + c;
    constexpr int GOF[17] = {0,0,0,0,0,1,2,1,2,1,2,3,4,3,4,3,4};
    #pragma unroll
    for (int k = 0; k < 17; ++k)
      og[k*256] = bf2f(xbf[k*XBSTR + c]) * a5[GOF[k]];
  }
}

extern "C" void kernel_launch(void* const* d_in, const int* in_sizes, int n_in,
                              void* d_out, int out_size, void* d_ws, size_t ws_size,
                              hipStream_t stream) {
    (void)n_in; (void)out_size;
    const float* x   = (const float*)d_in[0];
    const float* Wd  = (const float*)d_in[1];
    const float* bd  = (const float*)d_in[2];
    const float* s1  = (const float*)d_in[3];
    const float* b1  = (const float*)d_in[4];
    const float* m1  = (const float*)d_in[5];
    const float* v1  = (const float*)d_in[6];
    const float* Wc  = (const float*)d_in[7];
    const float* s2  = (const float*)d_in[8];
    const float* b2  = (const float*)d_in[9];
    const float* m2  = (const float*)d_in[10];
    const float* v2  = (const float*)d_in[11];
    const float* Wa  = (const float*)d_in[12];
    const float* ba  = (const float*)d_in[13];

    const int Btot = in_sizes[0] / (17 * 256);   // 4096 -> one block per batch
    bf16x8* wsf = (bf16x8*)d_ws;

    if (ws_size >= (size_t)FRAG_SLOTS * 16) {
        pack_frags<<<FRAG_SLOTS/256, 256, 0, stream>>>(Wd, Wc, Wa, wsf);
        fused_gnn_v9<true><<<Btot, 256, 0, stream>>>(
            x, Wd, bd, s1, b1, m1, v1, Wc, s2, b2, m2, v2, Wa, ba,
            wsf, (float*)d_out);
    } else {
        fused_gnn_v9<false><<<Btot, 256, 0, stream>>>(
            x, Wd, bd, s1, b1, m1, v1, Wc, s2, b2, m2, v2, Wa, ba,
            wsf, (float*)d_out);
    }
}

// Round 12
// 41.754 us; speedup vs baseline: 1.2682x; 1.1238x over previous
//
#include <hip/hip_runtime.h>

typedef float  v4f    __attribute__((ext_vector_type(4)));
typedef float  f32x4  __attribute__((ext_vector_type(4)));
typedef short  bf16x8 __attribute__((ext_vector_type(8)));

namespace {
constexpr int XBSTR = 264;   // xbf row stride (shorts)
constexpr int XDT   = 24;    // xdT row stride (shorts); 48 B, b128-aligned
constexpr int MWC   = 129;   // mw row stride (f32)
constexpr int ATS   = 258;   // att row stride (shorts)
constexpr int MSTR  = 72;    // mbf/abf row stride (shorts)
constexpr int FRAG_SLOTS = 5120;

__device__ __forceinline__ float fsilu(float v){ return v/(1.f+__expf(-v)); }
__device__ __forceinline__ float fsigm(float v){ return 1.f/(1.f+__expf(-v)); }

// fp32 pair -> packed bf16x2 via the HW instruction (1 VALU op / 2 elems)
__device__ __forceinline__ unsigned f2bf2(float a, float b){
  unsigned r;
  asm("v_cvt_pk_bf16_f32 %0, %1, %2" : "=v"(r) : "v"(a), "v"(b));
  return r;
}
__device__ __forceinline__ short f2bf(float f){   // scalar: RNE, matches cvt_pk
  unsigned u = __builtin_bit_cast(unsigned, f);
  return (short)((u + 0x7FFFu + ((u>>16)&1u)) >> 16);
}
__device__ __forceinline__ float bf2f(short s){
  unsigned u = ((unsigned)(unsigned short)s) << 16;
  return __builtin_bit_cast(float, u);
}

// ---- B-fragment getters: frag table in ws (fast) or on-the-fly (fallback) ----
template<bool USE_WS>
__device__ __forceinline__ bf16x8 get_bd(const bf16x8* wsf, const float* Wd,
                                         int nt, int ks, int l){
  if constexpr (USE_WS) return wsf[(nt*8 + ks)*64 + l];
  bf16x8 f;
  #pragma unroll
  for (int j = 0; j < 8; ++j) f[j] = f2bf(Wd[(ks*32 + (l>>4)*8 + j)*64 + nt*16 + (l&15)]);
  return f;
}
template<bool USE_WS>
__device__ __forceinline__ bf16x8 get_bc(const bf16x8* wsf, const float* Wc,
                                         int nt, int ks, int l){
  if constexpr (USE_WS) return wsf[2048 + (nt*2 + ks)*64 + l];
  const int col = nt*16 + (l&15), cw = col>>6, co = col&63;
  bf16x8 f;
  #pragma unroll
  for (int j = 0; j < 8; ++j) f[j] = f2bf(Wc[co*128 + cw*64 + ks*32 + (l>>4)*8 + j]);
  return f;
}
template<bool USE_WS>
__device__ __forceinline__ bf16x8 get_ba(const bf16x8* wsf, const float* Wa,
                                         int nt, int ks, int l){
  if constexpr (USE_WS) return wsf[3072 + (nt*2 + ks)*64 + l];
  const int col = nt*16 + (l&15);
  bf16x8 f;
  #pragma unroll
  for (int j = 0; j < 8; ++j) f[j] = f2bf(Wa[(ks*32 + (l>>4)*8 + j)*256 + col]);
  return f;
}
}

// ---- pre-kernel: pack Wd/Wc/Wa into bf16 MFMA B-fragment tables in ws ----
__global__ __launch_bounds__(256)
void pack_frags(const float* __restrict__ Wd, const float* __restrict__ Wc,
                const float* __restrict__ Wa, bf16x8* __restrict__ wsf)
{
  const int e  = blockIdx.x*256 + threadIdx.x;      // 0..5119
  const int l  = e & 63;
  const int fi = e >> 6;                            // 0..79
  bf16x8 f;
  if (fi < 32) {                                    // Bd: nt(4) x ks(8)
    const int nt = fi >> 3, ks = fi & 7;
    #pragma unroll
    for (int j = 0; j < 8; ++j) f[j] = f2bf(Wd[(ks*32 + (l>>4)*8 + j)*64 + nt*16 + (l&15)]);
  } else if (fi < 48) {                             // Bc: nt(8) x ks(2)
    const int idx = fi - 32, nt = idx >> 1, ks = idx & 1;
    const int col = nt*16 + (l&15), cw = col>>6, co = col&63;
    #pragma unroll
    for (int j = 0; j < 8; ++j) f[j] = f2bf(Wc[co*128 + cw*64 + ks*32 + (l>>4)*8 + j]);
  } else {                                          // Ba: nt(16) x ks(2)
    const int idx = fi - 48, nt = idx >> 1, ks = idx & 1;
    const int col = nt*16 + (l&15);
    #pragma unroll
    for (int j = 0; j < 8; ++j) f[j] = f2bf(Wa[(ks*32 + (l>>4)*8 + j)*256 + col]);
  }
  wsf[e] = f;
}

template<bool USE_WS>
__global__ __launch_bounds__(256, 6)
void fused_gnn_v10(const float* __restrict__ x,
                   const float* __restrict__ Wd, const float* __restrict__ bd,
                   const float* __restrict__ bn1s, const float* __restrict__ bn1b,
                   const float* __restrict__ bn1m, const float* __restrict__ bn1v,
                   const float* __restrict__ Wc,
                   const float* __restrict__ bn2s, const float* __restrict__ bn2b,
                   const float* __restrict__ bn2m, const float* __restrict__ bn2v,
                   const float* __restrict__ Wa, const float* __restrict__ ba,
                   const bf16x8* __restrict__ wsf,
                   float* __restrict__ out)
{
  // ~19.8 KB static LDS
  __shared__ short xbf[18*XBSTR];                   // 9504 B; row 17 = tail-clamp garbage target
  __shared__ __align__(16) char uni_raw[3072];      // union: xdT bf16[64][24] | att bf16[5][258]
  __shared__ float mw[5*MWC];                       // 2580 B
  __shared__ short mbf[16*MSTR];                    // 2304 B (rows 5-15 garbage)
  __shared__ short abf[16*MSTR];                    // 2304 B

  short* xdT = (short*)uni_raw;   // dead after B1 (bar3..5 separate from att writes)
  short* att = (short*)uni_raw;

  const int tid  = threadIdx.x;
  const int l    = tid & 63;
  const int wv   = tid >> 6;            // wave 0..3
  const int arow = l & 15;
  const int ak8  = (l >> 4) * 8;
  const int b    = blockIdx.x;          // one batch per block
  const int colA = wv*16 + arow;

  // ---- per-lane BN affines in registers (b_down folded into bn1 bias) ----
  const float a1r = bn1s[colA] * rsqrtf(bn1v[colA] + 1e-5f);
  const float b1r = (bd[colA] - bn1m[colA])*a1r + bn1b[colA];
  const float a2r = bn2s[l] * rsqrtf(bn2v[l] + 1e-5f);
  const float b2r = bn2b[l] - bn2m[l]*a2r;

  // ---- stage x -> bf16 LDS via cvt_pk (coalesced float4, 4.25 per thread) ----
  {
    const v4f* x4 = (const v4f*)(x + (size_t)b * 4352);
    #pragma unroll
    for (int i = 0; i < 5; ++i) {
      const int idx = i*256 + tid;
      if (idx < 1088) {
        const v4f v = x4[idx];
        const int r = idx >> 6, c4 = (idx & 63) * 4;
        uint2 u; u.x = f2bf2(v.x, v.y); u.y = f2bf2(v.z, v.w);
        *(uint2*)&xbf[r*XBSTR + c4] = u;
      }
    }
  }
  __syncthreads();                                   // bar1: stage -> A

  // ---- Phase A (MFMA): xd = silu(bn1(x @ Wd)), M=17, N=64, K=256; epilogue -> xdT ----
  {
    f32x4 acc0 = {0.f,0.f,0.f,0.f};                  // rows 0..15
    f32x4 acc1 = {0.f,0.f,0.f,0.f};                  // tail tile: row 0 = batch row 16
    const int rowT = (arow == 0) ? 16 : 17;          // tail rows 1..15 read garbage row 17, discarded
    #pragma unroll
    for (int h = 0; h < 2; ++h) {
      bf16x8 Bd[4];
      #pragma unroll
      for (int k4 = 0; k4 < 4; ++k4) Bd[k4] = get_bd<USE_WS>(wsf, Wd, wv, h*4 + k4, l);
      #pragma unroll
      for (int k4 = 0; k4 < 4; ++k4) {
        const int ks = h*4 + k4;
        bf16x8 a0 = *(const bf16x8*)&xbf[arow*XBSTR + ks*32 + ak8];
        acc0 = __builtin_amdgcn_mfma_f32_16x16x32_bf16(a0, Bd[k4], acc0, 0, 0, 0);
        bf16x8 a1 = *(const bf16x8*)&xbf[rowT*XBSTR + ks*32 + ak8];
        acc1 = __builtin_amdgcn_mfma_f32_16x16x32_bf16(a1, Bd[k4], acc1, 0, 0, 0);
      }
    }
    const float s0 = fsilu(acc0[0]*a1r + b1r);
    const float s1 = fsilu(acc0[1]*a1r + b1r);
    const float s2 = fsilu(acc0[2]*a1r + b1r);
    const float s3 = fsilu(acc0[3]*a1r + b1r);
    uint2 u; u.x = f2bf2(s0, s1); u.y = f2bf2(s2, s3);
    *(uint2*)&xdT[colA*XDT + (l>>4)*4] = u;          // rows (l>>4)*4..+3 of column colA
    if ((l >> 4) == 0)
      xdT[colA*XDT + 16] = f2bf(fsilu(acc1[0]*a1r + b1r));
  }
  __syncthreads();                                   // bar2: A -> B1 (xdT cross-wave)

  // ---- prefetch B2 weight frags (latency covered by B1 + bar3) ----
  bf16x8 BcT[2][2];
  #pragma unroll
  for (int t = 0; t < 2; ++t)
    #pragma unroll
    for (int ks = 0; ks < 2; ++ks)
      BcT[t][ks] = get_bc<USE_WS>(wsf, Wc, wv*2 + t, ks, l);

  // ---- Phase B1 (split): wave wv computes group g=wv; wave 0 also g=4 ----
  {
    const int i = l;
    #define XDV(r) bf2f(xdT[i*XDT + (r)])
    if (wv == 0) {
      const float m0 = (XDV(0)+XDV(1)+XDV(2)+XDV(3)+XDV(4))*0.2f;
      mbf[0*MSTR + i] = f2bf(m0);
      const float m4 = (XDV(12)+XDV(14)+XDV(16))*(1.f/3.f);
      mbf[4*MSTR + i] = f2bf(m4);
    } else if (wv == 1) {
      mbf[1*MSTR + i] = f2bf((XDV(5)+XDV(7)+XDV(9))*(1.f/3.f));
    } else if (wv == 2) {
      mbf[2*MSTR + i] = f2bf((XDV(6)+XDV(8)+XDV(10))*(1.f/3.f));
    } else {
      mbf[3*MSTR + i] = f2bf((XDV(11)+XDV(13)+XDV(15))*(1.f/3.f));
    }
    #undef XDV
  }
  __syncthreads();                                   // bar3: B1 -> B2 (mbf cross-wave)

  // ---- Phase B2 (MFMA): mw = means @ [Wc1|Wc2], M=5, N=128, wave owns 2 n-tiles ----
  {
    bf16x8 am[2];
    #pragma unroll
    for (int ks = 0; ks < 2; ++ks)
      am[ks] = *(const bf16x8*)&mbf[arow*MSTR + ks*32 + ak8];
    #pragma unroll
    for (int t = 0; t < 2; ++t) {
      const int nt = wv*2 + t;
      f32x4 acc = {0.f,0.f,0.f,0.f};
      #pragma unroll
      for (int ks = 0; ks < 2; ++ks)
        acc = __builtin_amdgcn_mfma_f32_16x16x32_bf16(am[ks], BcT[t][ks], acc, 0, 0, 0);
      #pragma unroll
      for (int j = 0; j < 4; ++j) {
        const int g = (l>>4)*4 + j;
        if (g < 5) mw[g*MWC + nt*16 + arow] = acc[j];
      }
    }
  }
  __syncthreads();                                   // bar4: B2 -> B3 (mw cross-wave)

  // ---- prefetch all phase-E weight frags (latency covered by B3 + bar5) ----
  bf16x8 BaT[4][2];
  #pragma unroll
  for (int t = 0; t < 4; ++t)
    #pragma unroll
    for (int ks = 0; ks < 2; ++ks)
      BaT[t][ks] = get_ba<USE_WS>(wsf, Wa, wv*4 + t, ks, l);

  // ---- Phase B3 (split): wave wv computes g=wv; wave 0 also g=4 ----
  {
    const int o = l;
    float m2c[5];
    #pragma unroll
    for (int cc = 0; cc < 5; ++cc) m2c[cc] = mw[cc*MWC + 64 + o];
    auto doG = [&](int g){
      const float bse = mw[g*MWC + o] - m2c[g];
      float s = 0.f;
      #pragma unroll
      for (int cc = 0; cc < 5; ++cc) {
        if (cc != g) s += fsilu((bse + m2c[cc])*a2r + b2r);
      }
      abf[g*MSTR + o] = f2bf(s);
    };
    if (wv == 0) { doG(0); doG(4); }
    else if (wv == 1) doG(1);
    else if (wv == 2) doG(2);
    else doG(3);
  }
  __syncthreads();                                   // bar5: B3 -> E (abf cross-wave)

  // ---- Phase E (MFMA): att = sigmoid(agg @ Wa + ba), M=5, N=256, wave owns 4 n-tiles ----
  {
    bf16x8 ae[2];
    #pragma unroll
    for (int ks = 0; ks < 2; ++ks)
      ae[ks] = *(const bf16x8*)&abf[arow*MSTR + ks*32 + ak8];
    #pragma unroll
    for (int t = 0; t < 4; ++t) {
      const int nt = wv*4 + t;
      const int colE = nt*16 + arow;
      f32x4 acc = {0.f,0.f,0.f,0.f};
      #pragma unroll
      for (int ks = 0; ks < 2; ++ks)
        acc = __builtin_amdgcn_mfma_f32_16x16x32_bf16(ae[ks], BaT[t][ks], acc, 0, 0, 0);
      const float bav = ba[colE];
      #pragma unroll
      for (int j = 0; j < 4; ++j) {
        const int g = (l>>4)*4 + j;
        if (g < 5) att[g*ATS + colE] = f2bf(fsigm(acc[j] + bav));
      }
    }
  }
  __syncthreads();                                   // bar6: E -> F

  // ---- Phase F: out[k][c] = bf16(x)[k][c] * att[GOF[k]][c] ----
  {
    const int c = tid;
    float a5[5];
    #pragma unroll
    for (int g = 0; g < 5; ++g) a5[g] = bf2f(att[g*ATS + c]);
    float* og = out + (size_t)b*4352 + c;
    constexpr int GOF[17] = {0,0,0,0,0,1,2,1,2,1,2,3,4,3,4,3,4};
    #pragma unroll
    for (int k = 0; k < 17; ++k)
      og[k*256] = bf2f(xbf[k*XBSTR + c]) * a5[GOF[k]];
  }
}

extern "C" void kernel_launch(void* const* d_in, const int* in_sizes, int n_in,
                              void* d_out, int out_size, void* d_ws, size_t ws_size,
                              hipStream_t stream) {
    (void)n_in; (void)out_size;
    const float* x   = (const float*)d_in[0];
    const float* Wd  = (const float*)d_in[1];
    const float* bd  = (const float*)d_in[2];
    const float* s1  = (const float*)d_in[3];
    const float* b1  = (const float*)d_in[4];
    const float* m1  = (const float*)d_in[5];
    const float* v1  = (const float*)d_in[6];
    const float* Wc  = (const float*)d_in[7];
    const float* s2  = (const float*)d_in[8];
    const float* b2  = (const float*)d_in[9];
    const float* m2  = (const float*)d_in[10];
    const float* v2  = (const float*)d_in[11];
    const float* Wa  = (const float*)d_in[12];
    const float* ba  = (const float*)d_in[13];

    const int Btot = in_sizes[0] / (17 * 256);   // 4096 -> one block per batch
    bf16x8* wsf = (bf16x8*)d_ws;

    if (ws_size >= (size_t)FRAG_SLOTS * 16) {
        pack_frags<<<FRAG_SLOTS/256, 256, 0, stream>>>(Wd, Wc, Wa, wsf);
        fused_gnn_v10<true><<<Btot, 256, 0, stream>>>(
            x, Wd, bd, s1, b1, m1, v1, Wc, s2, b2, m2, v2, Wa, ba,
            wsf, (float*)d_out);
    } else {
        fused_gnn_v10<false><<<Btot, 256, 0, stream>>>(
            x, Wd, bd, s1, b1, m1, v1, Wc, s2, b2, m2, v2, Wa, ba,
            wsf, (float*)d_out);
    }
}